// Round 9
// baseline (243.952 us; speedup 1.0000x reference)
//
#include <hip/hip_runtime.h>

#define N_ROWS   131072
#define D_IN     256
#define D_MID    128
#define N_SUBS   64

// ws layout: rowsum[N_ROWS] floats | gbins[128] (64 group sums | 64 counts)

// K1: 8 rows per wave, 8-lanes-per-row layout. Lane l: row = l>>3, q = l&7;
// loads the row's float4s at indices q+8k (k=0..7) -> each load instruction
// covers 8 rows x 128 B contiguous segments (fully coalesced), 8 KiB in
// flight per wave. Reduction: 31 VALU adds per lane, then just THREE
// shfl_xor (masks 1,2,4) reduce all 8 rows at once (vs 6-deep chain per row
// in the whole-row layout: 48 DS ops -> 3). Lanes q==0 store 8 consecutive
// floats (one 32 B transaction). Block 0 zeroes the group bins.
__global__ __launch_bounds__(256) void k1_rowsum(const float* __restrict__ x,
                                                 float* __restrict__ rowsum,
                                                 float* __restrict__ bins) {
    if (blockIdx.x == 0 && threadIdx.x < 2 * N_SUBS) bins[threadIdx.x] = 0.0f;
    int wave = blockIdx.x * 4 + (threadIdx.x >> 6);
    int lane = threadIdx.x & 63;
    int r    = lane >> 3;                 // 0..7: which of this wave's 8 rows
    int q    = lane & 7;                  // position within the row's 8 lanes
    int row0 = wave * 8;
    const float4* rowp = (const float4*)(x + (size_t)(row0 + r) * D_IN);

    float4 v[8];
    #pragma unroll
    for (int k = 0; k < 8; ++k) v[k] = rowp[q + 8 * k];   // 8 independent loads

    float s = 0.0f;
    #pragma unroll
    for (int k = 0; k < 8; ++k) s += (v[k].x + v[k].y) + (v[k].z + v[k].w);

    s += __shfl_xor(s, 1, 64);            // reduce across the 8 lanes of each
    s += __shfl_xor(s, 2, 64);            // row group — 3 DS ops total for all
    s += __shfl_xor(s, 4, 64);            // 8 rows

    if (q == 0) rowsum[row0 + r] = s;     // 8 lanes -> 32 B coalesced store
}

// K2: hierarchical group binning (proven shape). 128 blocks x 256 threads;
// each thread owns 4 rows via one float4 + one int4 load, 8 LDS atomics,
// then 128 global atomics per block (16K total -> no contention wall).
__global__ __launch_bounds__(256) void k2_group(const float* __restrict__ rowsum,
                                                const int* __restrict__ sub,
                                                float* __restrict__ gbins) {
    __shared__ float ls[2 * N_SUBS];
    int tid = threadIdx.x;
    if (tid < 2 * N_SUBS) ls[tid] = 0.0f;
    __syncthreads();

    int base = (blockIdx.x * 256 + tid) * 4;
    float4 rs = *(const float4*)(rowsum + base);
    int4   sg = *(const int4*)(sub + base);
    atomicAdd(&ls[sg.x], rs.x);  atomicAdd(&ls[N_SUBS + sg.x], 1.0f);
    atomicAdd(&ls[sg.y], rs.y);  atomicAdd(&ls[N_SUBS + sg.y], 1.0f);
    atomicAdd(&ls[sg.z], rs.z);  atomicAdd(&ls[N_SUBS + sg.z], 1.0f);
    atomicAdd(&ls[sg.w], rs.w);  atomicAdd(&ls[N_SUBS + sg.w], 1.0f);

    __syncthreads();
    if (tid < 2 * N_SUBS) atomicAdd(&gbins[tid], ls[tid]);
}

// K3: 4 rows per wave, straight-line (round-7 best-measured form). Lane-
// uniform float4/int4 loads for rowsum/sub, L2-hot scalar group lookups,
// then 4 independent 1 KiB broadcast stores. No LDS, no sync, no divergence.
__global__ __launch_bounds__(256) void k3_out(const float* __restrict__ rowsum,
                                              const int* __restrict__ sub,
                                              const float* __restrict__ gbins,
                                              const float* __restrict__ Gamma,
                                              const float* __restrict__ Lambda,
                                              float* __restrict__ out) {
    int wave = blockIdx.x * 4 + (threadIdx.x >> 6);
    int lane = threadIdx.x & 63;
    int row0 = wave * 4;
    float4 rs = *(const float4*)(rowsum + row0);   // lane-uniform 16 B
    int4   sg = *(const int4*)(sub + row0);        // lane-uniform 16 B
    float gam = Gamma[0], lam = Lambda[0];
    float rs0 = rowsum[0];                          // empty-group fallback term

    float o[4];
    int   g[4]  = {sg.x, sg.y, sg.z, sg.w};
    float r[4]  = {rs.x, rs.y, rs.z, rs.w};
    #pragma unroll
    for (int j = 0; j < 4; ++j) {
        float sum = gbins[g[j]];
        float cnt = gbins[N_SUBS + g[j]];
        float meansum = (cnt > 0.0f) ? (sum / cnt) : rs0;  // mean over x[0] fallback
        float s = gam * meansum;
        s = s > 0.0f ? s : 0.0f;                           // relu
        float t = lam * (r[j] + (float)D_MID * s);
        o[j] = t > 0.0f ? t : 0.0f;                        // relu
    }
    float4* dst = (float4*)(out + (size_t)row0 * D_IN);
    #pragma unroll
    for (int j = 0; j < 4; ++j)
        dst[(size_t)j * 64 + lane] = make_float4(o[j], o[j], o[j], o[j]);
}

extern "C" void kernel_launch(void* const* d_in, const int* in_sizes, int n_in,
                              void* d_out, int out_size, void* d_ws, size_t ws_size,
                              hipStream_t stream) {
    const float* x      = (const float*)d_in[0];
    const int*   sub    = (const int*)d_in[1];
    const float* Gamma  = (const float*)d_in[2];
    const float* Lambda = (const float*)d_in[3];
    float* out = (float*)d_out;

    float* rowsum = (float*)d_ws;                 // N_ROWS floats
    float* gbins  = rowsum + N_ROWS;              // 128 floats (sums | counts)

    k1_rowsum<<<N_ROWS / 32, 256, 0, stream>>>(x, rowsum, gbins);
    k2_group<<<128, 256, 0, stream>>>(rowsum, sub, gbins);
    k3_out<<<N_ROWS / 16, 256, 0, stream>>>(rowsum, sub, gbins, Gamma, Lambda, out);
}